// Round 9
// baseline (367.041 us; speedup 1.0000x reference)
//
#include <hip/hip_runtime.h>

// GCN forward + NCut loss on MI355X.
// R20: (a) k_fused1 REVERTED to R18/R14 structure (BK=64 single-buffer
//      global_load_lds; R19's BK=32 counted-vmcnt dbuf regressed: 2x
//      barriers + 1-tile-ahead insufficient vs ~900cy HBM latency).
//      (b) k_head + k_loss rebuilt with R13-style wide gathers: 2 lanes
//      per edge x 16B dwordx4 -> one gather instruction per 32 edges
//      (8x fewer memory instrs), one E-load per 32 edges, 5-level
//      shuffle reduce; head epilogue redistributes via per-wave LDS agg.
// loss = 16 - sum_j S_j/Gamma_j,  S_j = sum_e w_e Y[r,j] Y[c,j]

constexpr int NN = 50000;
constexpr int NE = 1600000;
constexpr int F0 = 512;
constexpr int F1 = 256;
constexpr int G  = 16;
constexpr int CB   = 196;      // coarse buckets: row>>8
constexpr int CCAP = 10240;    // capacity per coarse bucket (mean 8163)
constexpr int CHUNK = 4096;    // edges per passA block
constexpr int NPASS = 391;     // passA chunks (NE/CHUNK rounded up)
constexpr int ECH = 1024;      // k_spmm1 LDS E-chunk (recs)
// grid = 3*391 = 1173: stripe of 3 blocks = {GEMM, passA, GEMM}

typedef short  s16x8 __attribute__((ext_vector_type(8)));
typedef float  f32x4 __attribute__((ext_vector_type(4)));
typedef float  f32x2 __attribute__((ext_vector_type(2)));
typedef int    i32x4 __attribute__((ext_vector_type(4)));
typedef int    i32x2 __attribute__((ext_vector_type(2)));
typedef float  fv4   __attribute__((ext_vector_type(4)));

static __device__ __forceinline__ unsigned short f2bf(float f) {
    union { float f; unsigned u; } v; v.f = f;
    unsigned r = (v.u + 0x7FFFu + ((v.u >> 16) & 1u)) >> 16;   // RNE
    return (unsigned short)r;
}
static __device__ __forceinline__ float bf2f(unsigned short u) {
    union { unsigned u; float f; } v; v.u = (unsigned)u << 16;
    return v.f;
}

// async global->LDS, 16B per lane; lds addr must be wave-uniform (HW adds lane*16)
static __device__ __forceinline__ void glds16(const void* g, void* l) {
    __builtin_amdgcn_global_load_lds(
        (const __attribute__((address_space(1))) unsigned int*)g,
        (__attribute__((address_space(3))) unsigned int*)l,
        16, 0, 0);
}

// pack 8 f32 -> 8 bf16 (RNE), matching f2bf bit-exactly
static __device__ __forceinline__ s16x8 pack8(f32x4 a, f32x4 b) {
    union { unsigned u[4]; s16x8 v; } r;
    asm("v_cvt_pk_bf16_f32 %0, %1, %2" : "=v"(r.u[0]) : "v"(a.x), "v"(a.y));
    asm("v_cvt_pk_bf16_f32 %0, %1, %2" : "=v"(r.u[1]) : "v"(a.z), "v"(a.w));
    asm("v_cvt_pk_bf16_f32 %0, %1, %2" : "=v"(r.u[2]) : "v"(b.x), "v"(b.y));
    asm("v_cvt_pk_bf16_f32 %0, %1, %2" : "=v"(r.u[3]) : "v"(b.z), "v"(b.w));
    return r.v;
}

// ---------------- W1 pre-cast+transpose ----------------
__global__ __launch_bounds__(256) void k_castW1(const float* __restrict__ W1, unsigned short* __restrict__ W1t) {
    int idx = blockIdx.x * 256 + threadIdx.x;
    if (idx < F0 * F1) {
        int k = idx >> 8, n = idx & 255;
        W1t[n * F0 + k] = f2bf(W1[idx]);
    }
}

// ---------------- fused: GEMM1 (bf16 MFMA -> fp8 XW)  ∪  passA (coarse scatter) ----------------
__global__ __launch_bounds__(256) void k_fused1(const float* __restrict__ H,
                                                const unsigned short* __restrict__ W1t,
                                                unsigned char* __restrict__ XW,
                                                const int* __restrict__ row, const int* __restrict__ col,
                                                const float* __restrict__ ev,
                                                int* __restrict__ ccur, int2* __restrict__ cbuf) {
    // As: f32 [128][64] linear+swizzled slots, 32768 B | Bs: bf16 [128][64], 16384 B
    __shared__ __align__(16) unsigned char smem[49152];
    const int bid = blockIdx.x;
    const int tid = threadIdx.x;
    const int stripe = bid / 3;
    const int pos = bid - stripe * 3;      // 0,1,2

    if (pos != 1) {
        // ================= GEMM1 tile =================
        const int gidx = stripe * 2 + (pos >> 1);     // 0..781
        const int lane = tid & 63;
        const int wave = tid >> 6;
        const int bm = (gidx >> 1) * 128;
        const int bn = (gidx & 1) * 128;
        const int m_off = (wave & 1) * 64;
        const int n_off = (wave >> 1) * 64;
        const int l15  = lane & 15;
        const int quad = lane >> 4;

        f32x4 acc[4][4];
#pragma unroll
        for (int i = 0; i < 4; ++i)
#pragma unroll
            for (int j = 0; j < 4; ++j) acc[i][j] = (f32x4)0.f;

        // staging address precompute (swizzle: slot ^= row&7, within-row permute)
        const int arow16 = tid >> 4;                     // A: 16 lanes/row (256B row)
        const int slA    = (tid & 15) ^ (arow16 & 7);    // f32 slot16 source index
        const int browB  = tid >> 3;                     // B: 8 lanes/row (128B row)
        const int slB    = (tid & 7) ^ (browB & 7);      // bf16 slot16 source index
        const int wvB    = wave * 1024;                  // wave-uniform LDS sub-base

#define STAGE(K0)                                                              \
        do {                                                                   \
            _Pragma("unroll")                                                  \
            for (int p = 0; p < 8; ++p) {                                      \
                int gr = bm + p * 16 + arow16;                                 \
                gr = gr < NN ? gr : NN - 1;                                    \
                glds16(&H[(size_t)gr * F0 + (K0) + slA * 4],                   \
                       smem + p * 4096 + wvB);                                 \
            }                                                                  \
            _Pragma("unroll")                                                  \
            for (int p = 0; p < 4; ++p)                                        \
                glds16(&W1t[(size_t)(bn + p * 32 + browB) * F0 + (K0) + slB * 8], \
                       smem + 32768 + p * 4096 + wvB);                         \
        } while (0)

        STAGE(0);
        asm volatile("s_waitcnt vmcnt(0)" ::: "memory");
        __syncthreads();
        for (int k0 = 0; k0 < F0; k0 += 64) {
#pragma unroll
            for (int kk6 = 0; kk6 < 2; ++kk6) {
                const int kk = kk6 * 32;
                s16x8 af[4], bfr[4];
#pragma unroll
                for (int mi = 0; mi < 4; ++mi) {
                    const int r = m_off + mi * 16 + l15;
                    const int sw = r & 7;
                    const int s0 = (kk >> 2) + quad * 2;
                    const char* rb = (const char*)smem + r * 256;
                    f32x4 v0 = *(const f32x4*)(rb + (((s0    ) ^ sw) << 4));
                    f32x4 v1 = *(const f32x4*)(rb + (((s0 + 1) ^ sw) << 4));
                    af[mi] = pack8(v0, v1);
                }
#pragma unroll
                for (int ni = 0; ni < 4; ++ni) {
                    const int r = n_off + ni * 16 + l15;
                    const int sb = (kk >> 3) + quad;
                    bfr[ni] = *(const s16x8*)((const char*)smem + 32768 + r * 128
                                              + ((sb ^ (r & 7)) << 4));
                }
#pragma unroll
                for (int mi = 0; mi < 4; ++mi)
#pragma unroll
                    for (int ni = 0; ni < 4; ++ni)
                        acc[mi][ni] = __builtin_amdgcn_mfma_f32_16x16x32_bf16(af[mi], bfr[ni], acc[mi][ni], 0, 0, 0);
            }
            __syncthreads();                       // all waves done reading buffer
            if (k0 + 64 < F0) {
                STAGE(k0 + 64);
                asm volatile("s_waitcnt vmcnt(0)" ::: "memory");
            }
            __syncthreads();                       // staged data visible
        }
#undef STAGE
#pragma unroll
        for (int mi = 0; mi < 4; ++mi) {
            int r0 = bm + m_off + mi * 16 + quad * 4;
#pragma unroll
            for (int reg = 0; reg < 4; ++reg) {
                int gr = r0 + reg;
                if (gr < NN) {
                    unsigned char* orow = &XW[(size_t)gr * F1 + bn + n_off];
#pragma unroll
                    for (int ni = 0; ni < 4; ++ni) {
                        int pk = __builtin_amdgcn_cvt_pk_fp8_f32(acc[mi][ni][reg], 0.f, 0, false);
                        orow[ni * 16 + l15] = (unsigned char)(pk & 0xff);
                    }
                }
            }
        }
    } else {
        // ================= passA chunk =================
        int* hcnt  = (int*)smem;
        int* hbase = hcnt + CB;
        for (int i = tid; i < CB; i += 256) hcnt[i] = 0;
        __syncthreads();

        const int base4 = stripe * (CHUNK / 4);   // int4 units
        int recx[16]; float recw[16]; int cb[16];
#pragma unroll
        for (int k = 0; k < 4; ++k) {
            int i4 = base4 + k * 256 + tid;
            bool ok = i4 < NE / 4;
            i32x4 r = ok ? __builtin_nontemporal_load(&((const i32x4*)row)[i4]) : (i32x4)0;
            i32x4 c = ok ? __builtin_nontemporal_load(&((const i32x4*)col)[i4]) : (i32x4)0;
            fv4   w = ok ? __builtin_nontemporal_load(&((const fv4*)ev)[i4])   : (fv4)0.f;
            int rr[4] = {r.x, r.y, r.z, r.w};
            int cc[4] = {c.x, c.y, c.z, c.w};
            float ww[4] = {w.x, w.y, w.z, w.w};
#pragma unroll
            for (int j = 0; j < 4; ++j) {
                int slot = k * 4 + j;
                if (ok) {
                    cb[slot] = rr[j] >> 8;
                    atomicAdd(&hcnt[cb[slot]], 1);
                } else {
                    cb[slot] = -1;
                }
                recx[slot] = (cc[j] << 16) | (rr[j] & 255);
                recw[slot] = ww[j];
            }
        }
        __syncthreads();
        for (int i = tid; i < CB; i += 256) {
            int cnt = hcnt[i];
            hbase[i] = (cnt > 0) ? atomicAdd(&ccur[i], cnt) : 0;
            hcnt[i] = 0;                                   // reuse as local cursor
        }
        __syncthreads();
#pragma unroll
        for (int slot = 0; slot < 16; ++slot) {
            if (cb[slot] >= 0) {
                int p = hbase[cb[slot]] + atomicAdd(&hcnt[cb[slot]], 1);
                cbuf[(size_t)cb[slot] * CCAP + p] = make_int2(recx[slot], __float_as_int(recw[slot]));
            }
        }
    }
}

// ---------------- passB: build rowptr slice + fine scatter ----------------
__global__ __launch_bounds__(256) void k_passB(const int2* __restrict__ cbuf, const int* __restrict__ ccur,
                                               int* __restrict__ rowptr, int2* __restrict__ E) {
    __shared__ int cnt[256];
    __shared__ int scn[256];
    __shared__ int red[4];
    const int cbk = blockIdx.x;     // 0..195
    const int tid = threadIdx.x;
    cnt[tid] = 0;

    // base = sum(ccur[0..cbk))
    int b = 0;
    for (int i = tid; i < cbk; i += 256) b += ccur[i];
#pragma unroll
    for (int off = 1; off < 64; off <<= 1) b += __shfl_xor(b, off, 64);
    if ((tid & 63) == 0) red[tid >> 6] = b;
    __syncthreads();
    const int base = red[0] + red[1] + red[2] + red[3];

    const int total = ccur[cbk];
    const int2* src = cbuf + (size_t)cbk * CCAP;
    for (int i = tid; i < total; i += 256) atomicAdd(&cnt[src[i].x & 255], 1);
    __syncthreads();

    scn[tid] = cnt[tid];
    __syncthreads();
    for (int off = 1; off < 256; off <<= 1) {
        int t = (tid >= off) ? scn[tid - off] : 0;
        __syncthreads();
        scn[tid] += t;
        __syncthreads();
    }
    const int excl = scn[tid] - cnt[tid];
    const int r = (cbk << 8) + tid;
    if (r <= NN) rowptr[r] = base + excl;   // block 195 covers rowptr[NN]=NE
    __syncthreads();
    cnt[tid] = base + excl;                 // reuse as cursor
    __syncthreads();
    for (int i = tid; i < total; i += 256) {
        int2 rec = src[i];
        int rl = rec.x & 255;
        int c  = (int)((unsigned)rec.x >> 16);
        int p = atomicAdd(&cnt[rl], 1);
        E[p] = make_int2(c << 8, rec.y);
    }
}

// ---------------- SPMM1 + bias + relu + fused GEMM2 (fp8 gather, LDS-E + dbuf + pk_fma) ----------------
// W2 LDS layout: dword j*320 + lane16*20 + t (2-way banks = free).
// Block's E segment [rowptr[b*16], rowptr[b*16+16]) staged in LDS chunks.
__global__ __launch_bounds__(256) void k_spmm1(const unsigned char* __restrict__ XW, const int* __restrict__ rowptr,
                                               const int2* __restrict__ E,
                                               const float* __restrict__ b1, const float* __restrict__ W2,
                                               unsigned short* __restrict__ Z, float* __restrict__ Dv) {
    __shared__ float W2P[G * 320];   // 20480 B
    __shared__ i32x2 Esh[ECH];       // 8192 B
    const int tid = threadIdx.x;
#pragma unroll
    for (int it = 0; it < 16; ++it) {
        int elem = it * 256 + tid;            // 0..4095 = (j, l, t)
        int j = elem >> 8;
        int l = (elem >> 4) & 15;
        int t = elem & 15;
        W2P[j * 320 + l * 20 + t] = W2[(l * 16 + t) * 16 + j];
    }
    const int lane16 = tid & 15;
    const int loff = lane16 * 16;                   // byte offset into 256B fp8 row
    const int n = blockIdx.x * 16 + (tid >> 4);     // 16 nodes per block, 4 per wave
    const int nb0 = rowptr[blockIdx.x * 16];
    const int nb1 = rowptr[blockIdx.x * 16 + 16];
    const int s = rowptr[n];
    const int e = rowptr[n + 1];
    const i32x2* E2 = (const i32x2*)E;

    f32x2 acc2[8];                 // dim pairs: acc2[2q]=(4q,4q+1), acc2[2q+1]=(4q+2,4q+3)
#pragma unroll
    for (int q = 0; q < 8; ++q) acc2[q] = (f32x2)0.f;
    float wsum = 0.f;

#define GATH8(GG, WW, BASE)                                        \
        _Pragma("unroll")                                          \
        for (int k = 0; k < 8; ++k) {                              \
            i32x2 ed = Esh[(BASE) - w0 + k];                       \
            WW[k] = __int_as_float(ed.y);                          \
            GG[k] = *(const uint4*)(XW + ed.x + loff);             \
        }
#define COMP8(GG, WW)                                              \
        _Pragma("unroll")                                          \
        for (int k = 0; k < 8; ++k) {                              \
            const unsigned gw[4] = {GG[k].x, GG[k].y, GG[k].z, GG[k].w}; \
            f32x2 wp; wp.x = WW[k]; wp.y = WW[k];                  \
            _Pragma("unroll")                                      \
            for (int q = 0; q < 4; ++q) {                          \
                f32x2 lo = __builtin_amdgcn_cvt_pk_f32_fp8(gw[q], false); \
                f32x2 hi = __builtin_amdgcn_cvt_pk_f32_fp8(gw[q], true);  \
                acc2[2 * q]     = __builtin_elementwise_fma(lo, wp, acc2[2 * q]);     \
                acc2[2 * q + 1] = __builtin_elementwise_fma(hi, wp, acc2[2 * q + 1]); \
            }                                                      \
            wsum += WW[k];                                         \
        }

    for (int w0 = nb0; w0 < nb1; w0 += ECH) {
        const int wend = (w0 + ECH < nb1) ? (w0 + ECH) : nb1;
        __syncthreads();                    // all groups done with prev chunk
        for (int t = tid; t < wend - w0; t += 256)
            Esh[t] = __builtin_nontemporal_load(&E2[w0 + t]);
        __syncthreads();                    // chunk visible

        const int gs = (s > w0) ? s : w0;
        const int ge = (e < wend) ? e : wend;

        uint4 ggA[8], ggB[8];
        float wA[8], wB[8];
        int i = gs;
        if (i + 8 <= ge) { GATH8(ggA, wA, i) }
        while (i + 24 <= ge) {
            GATH8(ggB, wB, i + 8)
            COMP8(ggA, wA)
            GATH8(ggA, wA, i + 16)
            COMP8(ggB, wB)
            i += 16;
        }
        if (i + 16 <= ge) {
            GATH8(ggB, wB, i + 8)
            COMP8(ggA, wA)
            COMP8(ggB, wB)
            i += 16;
        } else if (i + 8 <= ge) {
            COMP8(ggA, wA)
            i += 8;
        }
        // tail < 8 recs
        for (; i < ge; i += 4) {
            int of4[4]; float w4v[4];
#pragma unroll
            for (int k = 0; k < 4; ++k) {
                int idx = i + k;
                bool ok = idx < ge;
                i32x2 ed = Esh[(ok ? idx : gs) - w0];
                of4[k] = ed.x; w4v[k] = ok ? __int_as_float(ed.y) : 0.f;
            }
            uint4 gg[4];
#pragma unroll
            for (int k = 0; k < 4; ++k)
                gg[k] = *(const uint4*)(XW + of4[k] + loff);
#pragma unroll
            for (int k = 0; k < 4; ++k) {
                const unsigned gw[4] = {gg[k].x, gg[k].y, gg[k].z, gg[k].w};
                f32x2 wp; wp.x = w4v[k]; wp.y = w4v[k];
#pragma unroll
                for (int q = 0; q < 4; ++q) {
                    f32x2 lo = __builtin_amdgcn_cvt_pk_f32_fp8(gw[q], false);
                    f32x2 hi = __builtin_amdgcn_cvt_pk_f32_fp8(gw[q], true);
                    acc2[2 * q]     = __builtin_elementwise_fma(lo, wp, acc2[2 * q]);
                    acc2[2 * q + 1] = __builtin_elementwise_fma(hi, wp, acc2[2 * q + 1]);
                }
                wsum += w4v[k];
            }
        }
    }
#undef GATH8
#undef COMP8

    if (lane16 == 0) Dv[n] = wsum;

    // h = relu(acc + b1), in place (lane owns dims loff..loff+15)
#pragma unroll
    for (int q = 0; q < 4; ++q) {
        float4 bb = *(const float4*)&b1[loff + q * 4];
        acc2[2 * q].x     = fmaxf(acc2[2 * q].x     + bb.x, 0.f);
        acc2[2 * q].y     = fmaxf(acc2[2 * q].y     + bb.y, 0.f);
        acc2[2 * q + 1].x = fmaxf(acc2[2 * q + 1].x + bb.z, 0.f);
        acc2[2 * q + 1].y = fmaxf(acc2[2 * q + 1].y + bb.w, 0.f);
    }

    float p[G];
#pragma unroll
    for (int j = 0; j < G; ++j) {
        float pj = 0.f;
#pragma unroll
        for (int q = 0; q < 4; ++q) {
            float4 w4 = *(const float4*)&W2P[j * 320 + lane16 * 20 + q * 4];
            pj += acc2[2 * q].x * w4.x + acc2[2 * q].y * w4.y
                + acc2[2 * q + 1].x * w4.z + acc2[2 * q + 1].y * w4.w;
        }
        p[j] = pj;
    }
    // reduce within each 16-lane group (4 levels)
#pragma unroll
    for (int off = 1; off < 16; off <<= 1) {
#pragma unroll
        for (int j = 0; j < G; ++j) p[j] += __shfl_xor(p[j], off, 64);
    }
    if (lane16 == 0) {
        unsigned zp[8];
#pragma unroll
        for (int j = 0; j < 8; ++j)
            zp[j] = (unsigned)f2bf(p[2 * j]) | ((unsigned)f2bf(p[2 * j + 1]) << 16);
        uint4* zo = (uint4*)&Z[n * G];
        zo[0] = make_uint4(zp[0], zp[1], zp[2], zp[3]);
        zo[1] = make_uint4(zp[4], zp[5], zp[6], zp[7]);
    }
}

// ---------------- SPMM2 + head + softmax + Gamma (wide gathers: 2 lanes/edge, 32 edges/wave) ----------------
__global__ __launch_bounds__(256) void k_head(const unsigned short* __restrict__ Zb, const int* __restrict__ rowptr,
                                              const int2* __restrict__ E,
                                              const float* __restrict__ b2, const float* __restrict__ Wl,
                                              const float* __restrict__ bl, const float* __restrict__ Dv,
                                              unsigned short* __restrict__ Yb, float* __restrict__ GammaP) {
    __shared__ float WlS[G * G];
    __shared__ float gsh[G];
    __shared__ float agg[4][G];
    const int tid = threadIdx.x;
    if (tid < G * G) WlS[tid] = Wl[tid];
    if (tid < G) gsh[tid] = 0.f;
    __syncthreads();
    const int lane = tid & 63;
    const int wv = tid >> 6;
    const int slot = lane >> 1;   // edge slot 0..31
    const int d2 = lane & 1;      // 16B half of the 32B row
    const int n = blockIdx.x * 4 + wv;
    const int s = __builtin_amdgcn_readfirstlane(rowptr[n]);
    const int e = __builtin_amdgcn_readfirstlane(rowptr[n + 1]);
    const char* Zc = (const char*)Zb;
    const i32x2* Ev = (const i32x2*)E;

    float acc[8];
#pragma unroll
    for (int q = 0; q < 8; ++q) acc[q] = 0.f;

    for (int base = s; base < e; base += 32) {
        int i = base + slot;
        bool ok = i < e;
        i32x2 rec = __builtin_nontemporal_load(&Ev[ok ? i : s]);
        float w = ok ? __int_as_float(rec.y) : 0.f;
        uint4 z = *(const uint4*)(Zc + (rec.x >> 3) + d2 * 16);   // 64 lanes = 32 rows
        const unsigned zz[4] = {z.x, z.y, z.z, z.w};
#pragma unroll
        for (int q = 0; q < 4; ++q) {
            acc[2 * q]     = fmaf(w, bf2f((unsigned short)(zz[q] & 0xffff)), acc[2 * q]);
            acc[2 * q + 1] = fmaf(w, bf2f((unsigned short)(zz[q] >> 16)),    acc[2 * q + 1]);
        }
    }
    // reduce across 32 edge slots (lane bits 1..5)
#pragma unroll
    for (int off = 2; off < 64; off <<= 1) {
#pragma unroll
        for (int q = 0; q < 8; ++q) acc[q] += __shfl_xor(acc[q], off, 64);
    }
    if (lane < 2) {
#pragma unroll
        for (int q = 0; q < 8; ++q) agg[wv][lane * 8 + q] = acc[q];
    }
    __syncthreads();

    const int j = lane & 15;
    float accj = agg[wv][j];

    float h2 = fmaxf(accj + b2[j], 0.f);
    float s3 = 0.f;
#pragma unroll
    for (int k = 0; k < G; ++k) s3 = fmaf(__shfl(h2, k, 64), WlS[k * G + j], s3);
    float h3 = fmaxf(s3 + bl[j], 0.f);
    float m = h3;
    m = fmaxf(m, __shfl_xor(m, 1, 64));
    m = fmaxf(m, __shfl_xor(m, 2, 64));
    m = fmaxf(m, __shfl_xor(m, 4, 64));
    m = fmaxf(m, __shfl_xor(m, 8, 64));
    float ex = __expf(h3 - m);
    float se = ex;
    se += __shfl_xor(se, 1, 64);
    se += __shfl_xor(se, 2, 64);
    se += __shfl_xor(se, 4, 64);
    se += __shfl_xor(se, 8, 64);
    float y = ex / se;
    if (lane < G) {
        Yb[n * G + j] = f2bf(y);
        atomicAdd(&gsh[j], y * Dv[n]);
    }
    __syncthreads();
    if (tid < G) atomicAdd(&GammaP[(blockIdx.x & 63) * G + tid], gsh[tid]);
}

// ---------------- edge loss numerators (wide gathers: 2 lanes/edge, 32 edges/wave) ----------------
__global__ __launch_bounds__(256) void k_loss(const unsigned short* __restrict__ Yb, const int* __restrict__ rowptr,
                                              const int2* __restrict__ E, float* __restrict__ SjP) {
    __shared__ float sjsh[G];
    const int tid = threadIdx.x;
    if (tid < G) sjsh[tid] = 0.f;
    __syncthreads();
    const int lane = tid & 63;
    const int slot = lane >> 1;
    const int d2 = lane & 1;
    const int n = blockIdx.x * 4 + (tid >> 6);
    const int s = __builtin_amdgcn_readfirstlane(rowptr[n]);
    const int e = __builtin_amdgcn_readfirstlane(rowptr[n + 1]);
    const char* Yc = (const char*)Yb;
    const i32x2* Ev = (const i32x2*)E;

    // own row slice: dims d2*8 .. d2*8+7
    uint4 yv = *(const uint4*)(Yc + ((size_t)n << 5) + d2 * 16);
    const unsigned yy[4] = {yv.x, yv.y, yv.z, yv.w};
    float yr[8];
#pragma unroll
    for (int q = 0; q < 4; ++q) {
        yr[2 * q]     = bf2f((unsigned short)(yy[q] & 0xffff));
        yr[2 * q + 1] = bf2f((unsigned short)(yy[q] >> 16));
    }

    float acc[8];
#pragma unroll
    for (int q = 0; q < 8; ++q) acc[q] = 0.f;

    for (int base = s; base < e; base += 32) {
        int i = base + slot;
        bool ok = i < e;
        i32x2 rec = __builtin_nontemporal_load(&Ev[ok ? i : s]);
        float w = ok ? __int_as_float(rec.y) : 0.f;
        uint4 z = *(const uint4*)(Yc + (rec.x >> 3) + d2 * 16);
        const unsigned zz[4] = {z.x, z.y, z.z, z.w};
#pragma unroll
        for (int q = 0; q < 4; ++q) {
            acc[2 * q]     = fmaf(w * yr[2 * q],     bf2f((unsigned short)(zz[q] & 0xffff)), acc[2 * q]);
            acc[2 * q + 1] = fmaf(w * yr[2 * q + 1], bf2f((unsigned short)(zz[q] >> 16)),    acc[2 * q + 1]);
        }
    }
    // reduce across 32 edge slots (lane bits 1..5)
#pragma unroll
    for (int off = 2; off < 64; off <<= 1) {
#pragma unroll
        for (int q = 0; q < 8; ++q) acc[q] += __shfl_xor(acc[q], off, 64);
    }
    if (lane < 2) {
#pragma unroll
        for (int q = 0; q < 8; ++q) atomicAdd(&sjsh[lane * 8 + q], acc[q]);
    }
    __syncthreads();
    if (tid < G) atomicAdd(&SjP[(blockIdx.x & 63) * G + tid], sjsh[tid]);
}

// ---------------- finalize: loss = 16 - sum_j S_j / Gamma_j ----------------
__global__ void k_final(const float* __restrict__ GammaP, const float* __restrict__ SjP,
                        float* __restrict__ out) {
    const int tid = threadIdx.x;   // 64 threads, j = tid&15 (dup groups harmless)
    const int j = tid & 15;
    float gam = 0.f, sj = 0.f;
    for (int b = 0; b < 64; ++b) {
        gam += GammaP[b * G + j];
        sj  += SjP[b * G + j];
    }
    float v = sj / gam;
    v += __shfl_xor(v, 1, 64);
    v += __shfl_xor(v, 2, 64);
    v += __shfl_xor(v, 4, 64);
    v += __shfl_xor(v, 8, 64);
    if (tid == 0) out[0] = 16.0f - v;
}

// ---------------- launcher ----------------
static inline size_t alignup(size_t x) { return (x + 255) & ~(size_t)255; }

extern "C" void kernel_launch(void* const* d_in, const int* in_sizes, int n_in,
                              void* d_out, int out_size, void* d_ws, size_t ws_size,
                              hipStream_t stream) {
    const float* H  = (const float*)d_in[0];
    const int*   ei = (const int*)d_in[1];
    const float* ev = (const float*)d_in[2];
    const float* W1 = (const float*)d_in[3];
    const float* b1 = (const float*)d_in[4];
    const float* W2 = (const float*)d_in[5];
    const float* b2 = (const float*)d_in[6];
    const float* Wl = (const float*)d_in[7];
    const float* bl = (const float*)d_in[8];
    const int* row = ei;
    const int* col = ei + NE;

    char* base = (char*)d_ws;
    size_t off = 0;
    unsigned char*  XW  = (unsigned char*)(base + off);  off = alignup(off + (size_t)NN * F1);
    unsigned short* W1t = (unsigned short*)(base + off); off = alignup(off + (size_t)F0 * F1 * 2);
    unsigned short* Z   = (unsigned short*)(base + off); off = alignup(off + (size_t)NN * G * 2);
    unsigned short* Yb  = (unsigned short*)(base + off); off = alignup(off + (size_t)NN * G * 2);
    float* Dv     = (float*)(base + off); off = alignup(off + (size_t)NN * 4);
    // zeroed region: ccur | GammaP | SjP (one memset)
    size_t zoff = off;
    int*   ccur   = (int*)(base + off);   off += (size_t)CB * 4;
    float* GammaP = (float*)(base + off); off += (size_t)64 * G * 4;
    float* SjP    = (float*)(base + off); off += (size_t)64 * G * 4;
    size_t zsize = off - zoff;
    off = alignup(off);
    int*   rowptr = (int*)(base + off);   off = alignup(off + (size_t)(NN + 1) * 4);
    int2*  cbuf   = (int2*)(base + off);  off = alignup(off + (size_t)CB * CCAP * 8);
    int2*  E      = (int2*)(base + off);  off = alignup(off + (size_t)NE * 8);

    hipMemsetAsync(base + zoff, 0, zsize, stream);

    k_castW1<<<dim3((F0 * F1 + 255) / 256), dim3(256), 0, stream>>>(W1, W1t);
    k_fused1<<<dim3(3 * NPASS), dim3(256), 0, stream>>>(
        H, W1t, XW, row, col, ev, ccur, cbuf);
    k_passB<<<dim3(CB), dim3(256), 0, stream>>>(cbuf, ccur, rowptr, E);
    k_spmm1<<<dim3(NN / 16), dim3(256), 0, stream>>>(XW, rowptr, E, b1, W2, Z, Dv);
    k_head<<<dim3(NN / 4), dim3(256), 0, stream>>>(Z, rowptr, E, b2, Wl, bl, Dv, Yb, GammaP);
    k_loss<<<dim3(NN / 4), dim3(256), 0, stream>>>(Yb, rowptr, E, SjP);
    k_final<<<dim3(1), dim3(64), 0, stream>>>(GammaP, SjP, (float*)d_out);
}

// Round 10
// 351.072 us; speedup vs baseline: 1.0455x; 1.0455x over previous
//
#include <hip/hip_runtime.h>

// GCN forward + NCut loss on MI355X.
// R21: full revert to R18 (best-known 354.4us) after R19/R20 structural
//      regressions. Single micro-fix kept: k_head's Wl matvec split across
//      the 4 duplicate lane groups (4 shfl + 2 shfl_xor instead of a
//      16-deep serial shfl+fma chain per node).
// loss = 16 - sum_j S_j/Gamma_j,  S_j = sum_e w_e Y[r,j] Y[c,j]

constexpr int NN = 50000;
constexpr int NE = 1600000;
constexpr int F0 = 512;
constexpr int F1 = 256;
constexpr int G  = 16;
constexpr int CB   = 196;      // coarse buckets: row>>8
constexpr int CCAP = 10240;    // capacity per coarse bucket (mean 8163)
constexpr int CHUNK = 4096;    // edges per passA block
constexpr int NPASS = 391;     // passA chunks (NE/CHUNK rounded up)
constexpr int ECH = 1024;      // k_spmm1 LDS E-chunk (recs)
// grid = 3*391 = 1173: stripe of 3 blocks = {GEMM, passA, GEMM}

typedef short  s16x8 __attribute__((ext_vector_type(8)));
typedef float  f32x4 __attribute__((ext_vector_type(4)));
typedef float  f32x2 __attribute__((ext_vector_type(2)));
typedef int    i32x4 __attribute__((ext_vector_type(4)));
typedef int    i32x2 __attribute__((ext_vector_type(2)));
typedef float  fv4   __attribute__((ext_vector_type(4)));

static __device__ __forceinline__ unsigned short f2bf(float f) {
    union { float f; unsigned u; } v; v.f = f;
    unsigned r = (v.u + 0x7FFFu + ((v.u >> 16) & 1u)) >> 16;   // RNE
    return (unsigned short)r;
}
static __device__ __forceinline__ float bf2f(unsigned short u) {
    union { unsigned u; float f; } v; v.u = (unsigned)u << 16;
    return v.f;
}

// async global->LDS, 16B per lane; lds addr must be wave-uniform (HW adds lane*16)
static __device__ __forceinline__ void glds16(const void* g, void* l) {
    __builtin_amdgcn_global_load_lds(
        (const __attribute__((address_space(1))) unsigned int*)g,
        (__attribute__((address_space(3))) unsigned int*)l,
        16, 0, 0);
}

// pack 8 f32 -> 8 bf16 (RNE), matching f2bf bit-exactly
static __device__ __forceinline__ s16x8 pack8(f32x4 a, f32x4 b) {
    union { unsigned u[4]; s16x8 v; } r;
    asm("v_cvt_pk_bf16_f32 %0, %1, %2" : "=v"(r.u[0]) : "v"(a.x), "v"(a.y));
    asm("v_cvt_pk_bf16_f32 %0, %1, %2" : "=v"(r.u[1]) : "v"(a.z), "v"(a.w));
    asm("v_cvt_pk_bf16_f32 %0, %1, %2" : "=v"(r.u[2]) : "v"(b.x), "v"(b.y));
    asm("v_cvt_pk_bf16_f32 %0, %1, %2" : "=v"(r.u[3]) : "v"(b.z), "v"(b.w));
    return r.v;
}

// ---------------- W1 pre-cast+transpose ----------------
__global__ __launch_bounds__(256) void k_castW1(const float* __restrict__ W1, unsigned short* __restrict__ W1t) {
    int idx = blockIdx.x * 256 + threadIdx.x;
    if (idx < F0 * F1) {
        int k = idx >> 8, n = idx & 255;
        W1t[n * F0 + k] = f2bf(W1[idx]);
    }
}

// ---------------- fused: GEMM1 (bf16 MFMA -> fp8 XW)  ∪  passA (coarse scatter) ----------------
__global__ __launch_bounds__(256) void k_fused1(const float* __restrict__ H,
                                                const unsigned short* __restrict__ W1t,
                                                unsigned char* __restrict__ XW,
                                                const int* __restrict__ row, const int* __restrict__ col,
                                                const float* __restrict__ ev,
                                                int* __restrict__ ccur, int2* __restrict__ cbuf) {
    // As: f32 [128][64] linear+swizzled slots, 32768 B | Bs: bf16 [128][64], 16384 B
    __shared__ __align__(16) unsigned char smem[49152];
    const int bid = blockIdx.x;
    const int tid = threadIdx.x;
    const int stripe = bid / 3;
    const int pos = bid - stripe * 3;      // 0,1,2

    if (pos != 1) {
        // ================= GEMM1 tile =================
        const int gidx = stripe * 2 + (pos >> 1);     // 0..781
        const int lane = tid & 63;
        const int wave = tid >> 6;
        const int bm = (gidx >> 1) * 128;
        const int bn = (gidx & 1) * 128;
        const int m_off = (wave & 1) * 64;
        const int n_off = (wave >> 1) * 64;
        const int l15  = lane & 15;
        const int quad = lane >> 4;

        f32x4 acc[4][4];
#pragma unroll
        for (int i = 0; i < 4; ++i)
#pragma unroll
            for (int j = 0; j < 4; ++j) acc[i][j] = (f32x4)0.f;

        // staging address precompute (swizzle: slot ^= row&7, within-row permute)
        const int arow16 = tid >> 4;                     // A: 16 lanes/row (256B row)
        const int slA    = (tid & 15) ^ (arow16 & 7);    // f32 slot16 source index
        const int browB  = tid >> 3;                     // B: 8 lanes/row (128B row)
        const int slB    = (tid & 7) ^ (browB & 7);      // bf16 slot16 source index
        const int wvB    = wave * 1024;                  // wave-uniform LDS sub-base

#define STAGE(K0)                                                              \
        do {                                                                   \
            _Pragma("unroll")                                                  \
            for (int p = 0; p < 8; ++p) {                                      \
                int gr = bm + p * 16 + arow16;                                 \
                gr = gr < NN ? gr : NN - 1;                                    \
                glds16(&H[(size_t)gr * F0 + (K0) + slA * 4],                   \
                       smem + p * 4096 + wvB);                                 \
            }                                                                  \
            _Pragma("unroll")                                                  \
            for (int p = 0; p < 4; ++p)                                        \
                glds16(&W1t[(size_t)(bn + p * 32 + browB) * F0 + (K0) + slB * 8], \
                       smem + 32768 + p * 4096 + wvB);                         \
        } while (0)

        STAGE(0);
        asm volatile("s_waitcnt vmcnt(0)" ::: "memory");
        __syncthreads();
        for (int k0 = 0; k0 < F0; k0 += 64) {
#pragma unroll
            for (int kk6 = 0; kk6 < 2; ++kk6) {
                const int kk = kk6 * 32;
                s16x8 af[4], bfr[4];
#pragma unroll
                for (int mi = 0; mi < 4; ++mi) {
                    const int r = m_off + mi * 16 + l15;
                    const int sw = r & 7;
                    const int s0 = (kk >> 2) + quad * 2;
                    const char* rb = (const char*)smem + r * 256;
                    f32x4 v0 = *(const f32x4*)(rb + (((s0    ) ^ sw) << 4));
                    f32x4 v1 = *(const f32x4*)(rb + (((s0 + 1) ^ sw) << 4));
                    af[mi] = pack8(v0, v1);
                }
#pragma unroll
                for (int ni = 0; ni < 4; ++ni) {
                    const int r = n_off + ni * 16 + l15;
                    const int sb = (kk >> 3) + quad;
                    bfr[ni] = *(const s16x8*)((const char*)smem + 32768 + r * 128
                                              + ((sb ^ (r & 7)) << 4));
                }
#pragma unroll
                for (int mi = 0; mi < 4; ++mi)
#pragma unroll
                    for (int ni = 0; ni < 4; ++ni)
                        acc[mi][ni] = __builtin_amdgcn_mfma_f32_16x16x32_bf16(af[mi], bfr[ni], acc[mi][ni], 0, 0, 0);
            }
            __syncthreads();                       // all waves done reading buffer
            if (k0 + 64 < F0) {
                STAGE(k0 + 64);
                asm volatile("s_waitcnt vmcnt(0)" ::: "memory");
            }
            __syncthreads();                       // staged data visible
        }
#undef STAGE
#pragma unroll
        for (int mi = 0; mi < 4; ++mi) {
            int r0 = bm + m_off + mi * 16 + quad * 4;
#pragma unroll
            for (int reg = 0; reg < 4; ++reg) {
                int gr = r0 + reg;
                if (gr < NN) {
                    unsigned char* orow = &XW[(size_t)gr * F1 + bn + n_off];
#pragma unroll
                    for (int ni = 0; ni < 4; ++ni) {
                        int pk = __builtin_amdgcn_cvt_pk_fp8_f32(acc[mi][ni][reg], 0.f, 0, false);
                        orow[ni * 16 + l15] = (unsigned char)(pk & 0xff);
                    }
                }
            }
        }
    } else {
        // ================= passA chunk =================
        int* hcnt  = (int*)smem;
        int* hbase = hcnt + CB;
        for (int i = tid; i < CB; i += 256) hcnt[i] = 0;
        __syncthreads();

        const int base4 = stripe * (CHUNK / 4);   // int4 units
        int recx[16]; float recw[16]; int cb[16];
#pragma unroll
        for (int k = 0; k < 4; ++k) {
            int i4 = base4 + k * 256 + tid;
            bool ok = i4 < NE / 4;
            i32x4 r = ok ? __builtin_nontemporal_load(&((const i32x4*)row)[i4]) : (i32x4)0;
            i32x4 c = ok ? __builtin_nontemporal_load(&((const i32x4*)col)[i4]) : (i32x4)0;
            fv4   w = ok ? __builtin_nontemporal_load(&((const fv4*)ev)[i4])   : (fv4)0.f;
            int rr[4] = {r.x, r.y, r.z, r.w};
            int cc[4] = {c.x, c.y, c.z, c.w};
            float ww[4] = {w.x, w.y, w.z, w.w};
#pragma unroll
            for (int j = 0; j < 4; ++j) {
                int slot = k * 4 + j;
                if (ok) {
                    cb[slot] = rr[j] >> 8;
                    atomicAdd(&hcnt[cb[slot]], 1);
                } else {
                    cb[slot] = -1;
                }
                recx[slot] = (cc[j] << 16) | (rr[j] & 255);
                recw[slot] = ww[j];
            }
        }
        __syncthreads();
        for (int i = tid; i < CB; i += 256) {
            int cnt = hcnt[i];
            hbase[i] = (cnt > 0) ? atomicAdd(&ccur[i], cnt) : 0;
            hcnt[i] = 0;                                   // reuse as local cursor
        }
        __syncthreads();
#pragma unroll
        for (int slot = 0; slot < 16; ++slot) {
            if (cb[slot] >= 0) {
                int p = hbase[cb[slot]] + atomicAdd(&hcnt[cb[slot]], 1);
                cbuf[(size_t)cb[slot] * CCAP + p] = make_int2(recx[slot], __float_as_int(recw[slot]));
            }
        }
    }
}

// ---------------- passB: build rowptr slice + fine scatter ----------------
__global__ __launch_bounds__(256) void k_passB(const int2* __restrict__ cbuf, const int* __restrict__ ccur,
                                               int* __restrict__ rowptr, int2* __restrict__ E) {
    __shared__ int cnt[256];
    __shared__ int scn[256];
    __shared__ int red[4];
    const int cbk = blockIdx.x;     // 0..195
    const int tid = threadIdx.x;
    cnt[tid] = 0;

    // base = sum(ccur[0..cbk))
    int b = 0;
    for (int i = tid; i < cbk; i += 256) b += ccur[i];
#pragma unroll
    for (int off = 1; off < 64; off <<= 1) b += __shfl_xor(b, off, 64);
    if ((tid & 63) == 0) red[tid >> 6] = b;
    __syncthreads();
    const int base = red[0] + red[1] + red[2] + red[3];

    const int total = ccur[cbk];
    const int2* src = cbuf + (size_t)cbk * CCAP;
    for (int i = tid; i < total; i += 256) atomicAdd(&cnt[src[i].x & 255], 1);
    __syncthreads();

    scn[tid] = cnt[tid];
    __syncthreads();
    for (int off = 1; off < 256; off <<= 1) {
        int t = (tid >= off) ? scn[tid - off] : 0;
        __syncthreads();
        scn[tid] += t;
        __syncthreads();
    }
    const int excl = scn[tid] - cnt[tid];
    const int r = (cbk << 8) + tid;
    if (r <= NN) rowptr[r] = base + excl;   // block 195 covers rowptr[NN]=NE
    __syncthreads();
    cnt[tid] = base + excl;                 // reuse as cursor
    __syncthreads();
    for (int i = tid; i < total; i += 256) {
        int2 rec = src[i];
        int rl = rec.x & 255;
        int c  = (int)((unsigned)rec.x >> 16);
        int p = atomicAdd(&cnt[rl], 1);
        E[p] = make_int2(c << 8, rec.y);
    }
}

// ---------------- SPMM1 + bias + relu + fused GEMM2 (fp8 gather, LDS-E + dbuf + pk_fma) ----------------
// W2 LDS layout: dword j*320 + lane16*20 + t (2-way banks = free).
// Block's E segment [rowptr[b*16], rowptr[b*16+16]) staged in LDS chunks.
__global__ __launch_bounds__(256) void k_spmm1(const unsigned char* __restrict__ XW, const int* __restrict__ rowptr,
                                               const int2* __restrict__ E,
                                               const float* __restrict__ b1, const float* __restrict__ W2,
                                               unsigned short* __restrict__ Z, float* __restrict__ Dv) {
    __shared__ float W2P[G * 320];   // 20480 B
    __shared__ i32x2 Esh[ECH];       // 8192 B
    const int tid = threadIdx.x;
#pragma unroll
    for (int it = 0; it < 16; ++it) {
        int elem = it * 256 + tid;            // 0..4095 = (j, l, t)
        int j = elem >> 8;
        int l = (elem >> 4) & 15;
        int t = elem & 15;
        W2P[j * 320 + l * 20 + t] = W2[(l * 16 + t) * 16 + j];
    }
    const int lane16 = tid & 15;
    const int loff = lane16 * 16;                   // byte offset into 256B fp8 row
    const int n = blockIdx.x * 16 + (tid >> 4);     // 16 nodes per block, 4 per wave
    const int nb0 = rowptr[blockIdx.x * 16];
    const int nb1 = rowptr[blockIdx.x * 16 + 16];
    const int s = rowptr[n];
    const int e = rowptr[n + 1];
    const i32x2* E2 = (const i32x2*)E;

    f32x2 acc2[8];                 // dim pairs: acc2[2q]=(4q,4q+1), acc2[2q+1]=(4q+2,4q+3)
#pragma unroll
    for (int q = 0; q < 8; ++q) acc2[q] = (f32x2)0.f;
    float wsum = 0.f;

#define GATH8(GG, WW, BASE)                                        \
        _Pragma("unroll")                                          \
        for (int k = 0; k < 8; ++k) {                              \
            i32x2 ed = Esh[(BASE) - w0 + k];                       \
            WW[k] = __int_as_float(ed.y);                          \
            GG[k] = *(const uint4*)(XW + ed.x + loff);             \
        }
#define COMP8(GG, WW)                                              \
        _Pragma("unroll")                                          \
        for (int k = 0; k < 8; ++k) {                              \
            const unsigned gw[4] = {GG[k].x, GG[k].y, GG[k].z, GG[k].w}; \
            f32x2 wp; wp.x = WW[k]; wp.y = WW[k];                  \
            _Pragma("unroll")                                      \
            for (int q = 0; q < 4; ++q) {                          \
                f32x2 lo = __builtin_amdgcn_cvt_pk_f32_fp8(gw[q], false); \
                f32x2 hi = __builtin_amdgcn_cvt_pk_f32_fp8(gw[q], true);  \
                acc2[2 * q]     = __builtin_elementwise_fma(lo, wp, acc2[2 * q]);     \
                acc2[2 * q + 1] = __builtin_elementwise_fma(hi, wp, acc2[2 * q + 1]); \
            }                                                      \
            wsum += WW[k];                                         \
        }

    for (int w0 = nb0; w0 < nb1; w0 += ECH) {
        const int wend = (w0 + ECH < nb1) ? (w0 + ECH) : nb1;
        __syncthreads();                    // all groups done with prev chunk
        for (int t = tid; t < wend - w0; t += 256)
            Esh[t] = __builtin_nontemporal_load(&E2[w0 + t]);
        __syncthreads();                    // chunk visible

        const int gs = (s > w0) ? s : w0;
        const int ge = (e < wend) ? e : wend;

        uint4 ggA[8], ggB[8];
        float wA[8], wB[8];
        int i = gs;
        if (i + 8 <= ge) { GATH8(ggA, wA, i) }
        while (i + 24 <= ge) {
            GATH8(ggB, wB, i + 8)
            COMP8(ggA, wA)
            GATH8(ggA, wA, i + 16)
            COMP8(ggB, wB)
            i += 16;
        }
        if (i + 16 <= ge) {
            GATH8(ggB, wB, i + 8)
            COMP8(ggA, wA)
            COMP8(ggB, wB)
            i += 16;
        } else if (i + 8 <= ge) {
            COMP8(ggA, wA)
            i += 8;
        }
        // tail < 8 recs
        for (; i < ge; i += 4) {
            int of4[4]; float w4v[4];
#pragma unroll
            for (int k = 0; k < 4; ++k) {
                int idx = i + k;
                bool ok = idx < ge;
                i32x2 ed = Esh[(ok ? idx : gs) - w0];
                of4[k] = ed.x; w4v[k] = ok ? __int_as_float(ed.y) : 0.f;
            }
            uint4 gg[4];
#pragma unroll
            for (int k = 0; k < 4; ++k)
                gg[k] = *(const uint4*)(XW + of4[k] + loff);
#pragma unroll
            for (int k = 0; k < 4; ++k) {
                const unsigned gw[4] = {gg[k].x, gg[k].y, gg[k].z, gg[k].w};
                f32x2 wp; wp.x = w4v[k]; wp.y = w4v[k];
#pragma unroll
                for (int q = 0; q < 4; ++q) {
                    f32x2 lo = __builtin_amdgcn_cvt_pk_f32_fp8(gw[q], false);
                    f32x2 hi = __builtin_amdgcn_cvt_pk_f32_fp8(gw[q], true);
                    acc2[2 * q]     = __builtin_elementwise_fma(lo, wp, acc2[2 * q]);
                    acc2[2 * q + 1] = __builtin_elementwise_fma(hi, wp, acc2[2 * q + 1]);
                }
                wsum += w4v[k];
            }
        }
    }
#undef GATH8
#undef COMP8

    if (lane16 == 0) Dv[n] = wsum;

    // h = relu(acc + b1), in place (lane owns dims loff..loff+15)
#pragma unroll
    for (int q = 0; q < 4; ++q) {
        float4 bb = *(const float4*)&b1[loff + q * 4];
        acc2[2 * q].x     = fmaxf(acc2[2 * q].x     + bb.x, 0.f);
        acc2[2 * q].y     = fmaxf(acc2[2 * q].y     + bb.y, 0.f);
        acc2[2 * q + 1].x = fmaxf(acc2[2 * q + 1].x + bb.z, 0.f);
        acc2[2 * q + 1].y = fmaxf(acc2[2 * q + 1].y + bb.w, 0.f);
    }

    float p[G];
#pragma unroll
    for (int j = 0; j < G; ++j) {
        float pj = 0.f;
#pragma unroll
        for (int q = 0; q < 4; ++q) {
            float4 w4 = *(const float4*)&W2P[j * 320 + lane16 * 20 + q * 4];
            pj += acc2[2 * q].x * w4.x + acc2[2 * q].y * w4.y
                + acc2[2 * q + 1].x * w4.z + acc2[2 * q + 1].y * w4.w;
        }
        p[j] = pj;
    }
    // reduce within each 16-lane group (4 levels)
#pragma unroll
    for (int off = 1; off < 16; off <<= 1) {
#pragma unroll
        for (int j = 0; j < G; ++j) p[j] += __shfl_xor(p[j], off, 64);
    }
    if (lane16 == 0) {
        unsigned zp[8];
#pragma unroll
        for (int j = 0; j < 8; ++j)
            zp[j] = (unsigned)f2bf(p[2 * j]) | ((unsigned)f2bf(p[2 * j + 1]) << 16);
        uint4* zo = (uint4*)&Z[n * G];
        zo[0] = make_uint4(zp[0], zp[1], zp[2], zp[3]);
        zo[1] = make_uint4(zp[4], zp[5], zp[6], zp[7]);
    }
}

// ---------------- SPMM2 + head + softmax + Gamma ----------------
__global__ __launch_bounds__(256) void k_head(const unsigned short* __restrict__ Zb, const int* __restrict__ rowptr,
                                              const int2* __restrict__ E,
                                              const float* __restrict__ b2, const float* __restrict__ Wl,
                                              const float* __restrict__ bl, const float* __restrict__ Dv,
                                              unsigned short* __restrict__ Yb, float* __restrict__ GammaP) {
    __shared__ float WlS[G * G];
    __shared__ float gsh[G];
    const int tid = threadIdx.x;
    if (tid < G * G) WlS[tid] = Wl[tid];
    if (tid < G) gsh[tid] = 0.f;
    __syncthreads();
    const int lane = tid & 63;
    const int g = lane >> 3;      // edge slot 0..7
    const int d = lane & 7;       // dword in Z row
    const int n = blockIdx.x * 4 + (tid >> 6);
    const int s = __builtin_amdgcn_readfirstlane(rowptr[n]);
    const int e = __builtin_amdgcn_readfirstlane(rowptr[n + 1]);
    const char* Zc = (const char*)Zb;
    const i32x2* Ev = (const i32x2*)E;

    float a0 = 0.f, a1 = 0.f;
    for (int base = s; base < e; base += 16) {
        int i0 = base + g;
        int i1 = base + 8 + g;
        i32x2 e0 = __builtin_nontemporal_load(&Ev[(i0 < e) ? i0 : s]);
        i32x2 e1 = __builtin_nontemporal_load(&Ev[(i1 < e) ? i1 : s]);
        float w0 = (i0 < e) ? __int_as_float(e0.y) : 0.f;
        float w1 = (i1 < e) ? __int_as_float(e1.y) : 0.f;
        unsigned z0 = *(const unsigned*)(Zc + (e0.x >> 3) + d * 4);
        unsigned z1 = *(const unsigned*)(Zc + (e1.x >> 3) + d * 4);
        a0 = fmaf(w0, bf2f((unsigned short)(z0 & 0xffff)), a0);
        a1 = fmaf(w0, bf2f((unsigned short)(z0 >> 16)), a1);
        a0 = fmaf(w1, bf2f((unsigned short)(z1 & 0xffff)), a0);
        a1 = fmaf(w1, bf2f((unsigned short)(z1 >> 16)), a1);
    }
    a0 += __shfl_xor(a0, 8, 64);  a1 += __shfl_xor(a1, 8, 64);
    a0 += __shfl_xor(a0, 16, 64); a1 += __shfl_xor(a1, 16, 64);
    a0 += __shfl_xor(a0, 32, 64); a1 += __shfl_xor(a1, 32, 64);

    const int j = lane & 15;
    float e0v = __shfl(a0, j >> 1, 64);
    float e1v = __shfl(a1, j >> 1, 64);
    float accj = (j & 1) ? e1v : e0v;

    float h2 = fmaxf(accj + b2[j], 0.f);
    // Wl matvec split across the 4 duplicate lane groups: each group
    // computes 4 k-terms, then 2 shfl_xor combine (serial chain 16 -> 6).
    const int qg = lane >> 4;
    float s3p = 0.f;
#pragma unroll
    for (int t = 0; t < 4; ++t) {
        int k = qg * 4 + t;
        s3p = fmaf(__shfl(h2, k, 64), WlS[k * G + j], s3p);
    }
    s3p += __shfl_xor(s3p, 16, 64);
    s3p += __shfl_xor(s3p, 32, 64);
    float s3 = s3p;
    float h3 = fmaxf(s3 + bl[j], 0.f);
    float m = h3;
    m = fmaxf(m, __shfl_xor(m, 1, 64));
    m = fmaxf(m, __shfl_xor(m, 2, 64));
    m = fmaxf(m, __shfl_xor(m, 4, 64));
    m = fmaxf(m, __shfl_xor(m, 8, 64));
    float ex = __expf(h3 - m);
    float se = ex;
    se += __shfl_xor(se, 1, 64);
    se += __shfl_xor(se, 2, 64);
    se += __shfl_xor(se, 4, 64);
    se += __shfl_xor(se, 8, 64);
    float y = ex / se;
    if (lane < G) {
        Yb[n * G + j] = f2bf(y);
        atomicAdd(&gsh[j], y * Dv[n]);
    }
    __syncthreads();
    if (tid < G) atomicAdd(&GammaP[(blockIdx.x & 63) * G + tid], gsh[tid]);
}

// ---------------- edge loss numerators: S_j = sum_e w Y[r,j]Y[c,j] (slotted) ----------------
__global__ __launch_bounds__(256) void k_loss(const unsigned short* __restrict__ Yb, const int* __restrict__ rowptr,
                                              const int2* __restrict__ E, float* __restrict__ SjP) {
    __shared__ float sjsh[G];
    const int tid = threadIdx.x;
    if (tid < G) sjsh[tid] = 0.f;
    __syncthreads();
    const int lane = tid & 63;
    const int g = lane >> 3;
    const int d = lane & 7;
    const int n = blockIdx.x * 4 + (tid >> 6);
    const int s = __builtin_amdgcn_readfirstlane(rowptr[n]);
    const int e = __builtin_amdgcn_readfirstlane(rowptr[n + 1]);
    const char* Yc = (const char*)Yb;
    const i32x2* Ev = (const i32x2*)E;

    unsigned yr = *(const unsigned*)(Yc + ((size_t)n << 5) + d * 4);
    float y0 = bf2f((unsigned short)(yr & 0xffff));
    float y1 = bf2f((unsigned short)(yr >> 16));

    float s0 = 0.f, s1 = 0.f;
    for (int base = s; base < e; base += 16) {
        int i0 = base + g;
        int i1 = base + 8 + g;
        i32x2 e0 = __builtin_nontemporal_load(&Ev[(i0 < e) ? i0 : s]);
        i32x2 e1 = __builtin_nontemporal_load(&Ev[(i1 < e) ? i1 : s]);
        float w0 = (i0 < e) ? __int_as_float(e0.y) : 0.f;
        float w1 = (i1 < e) ? __int_as_float(e1.y) : 0.f;
        unsigned z0 = *(const unsigned*)(Yc + (e0.x >> 3) + d * 4);
        unsigned z1 = *(const unsigned*)(Yc + (e1.x >> 3) + d * 4);
        s0 = fmaf(w0 * y0, bf2f((unsigned short)(z0 & 0xffff)), s0);
        s1 = fmaf(w0 * y1, bf2f((unsigned short)(z0 >> 16)), s1);
        s0 = fmaf(w1 * y0, bf2f((unsigned short)(z1 & 0xffff)), s0);
        s1 = fmaf(w1 * y1, bf2f((unsigned short)(z1 >> 16)), s1);
    }
    // sum over the 8 edge-slot groups (bits 3..5 of lane)
    s0 += __shfl_xor(s0, 8, 64);  s1 += __shfl_xor(s1, 8, 64);
    s0 += __shfl_xor(s0, 16, 64); s1 += __shfl_xor(s1, 16, 64);
    s0 += __shfl_xor(s0, 32, 64); s1 += __shfl_xor(s1, 32, 64);
    if (lane < 8) {
        atomicAdd(&sjsh[2 * lane],     s0);
        atomicAdd(&sjsh[2 * lane + 1], s1);
    }
    __syncthreads();
    if (tid < G) atomicAdd(&SjP[(blockIdx.x & 63) * G + tid], sjsh[tid]);
}

// ---------------- finalize: loss = 16 - sum_j S_j / Gamma_j ----------------
__global__ void k_final(const float* __restrict__ GammaP, const float* __restrict__ SjP,
                        float* __restrict__ out) {
    const int tid = threadIdx.x;   // 64 threads, j = tid&15 (dup groups harmless)
    const int j = tid & 15;
    float gam = 0.f, sj = 0.f;
    for (int b = 0; b < 64; ++b) {
        gam += GammaP[b * G + j];
        sj  += SjP[b * G + j];
    }
    float v = sj / gam;
    v += __shfl_xor(v, 1, 64);
    v += __shfl_xor(v, 2, 64);
    v += __shfl_xor(v, 4, 64);
    v += __shfl_xor(v, 8, 64);
    if (tid == 0) out[0] = 16.0f - v;
}

// ---------------- launcher ----------------
static inline size_t alignup(size_t x) { return (x + 255) & ~(size_t)255; }

extern "C" void kernel_launch(void* const* d_in, const int* in_sizes, int n_in,
                              void* d_out, int out_size, void* d_ws, size_t ws_size,
                              hipStream_t stream) {
    const float* H  = (const float*)d_in[0];
    const int*   ei = (const int*)d_in[1];
    const float* ev = (const float*)d_in[2];
    const float* W1 = (const float*)d_in[3];
    const float* b1 = (const float*)d_in[4];
    const float* W2 = (const float*)d_in[5];
    const float* b2 = (const float*)d_in[6];
    const float* Wl = (const float*)d_in[7];
    const float* bl = (const float*)d_in[8];
    const int* row = ei;
    const int* col = ei + NE;

    char* base = (char*)d_ws;
    size_t off = 0;
    unsigned char*  XW  = (unsigned char*)(base + off);  off = alignup(off + (size_t)NN * F1);
    unsigned short* W1t = (unsigned short*)(base + off); off = alignup(off + (size_t)F0 * F1 * 2);
    unsigned short* Z   = (unsigned short*)(base + off); off = alignup(off + (size_t)NN * G * 2);
    unsigned short* Yb  = (unsigned short*)(base + off); off = alignup(off + (size_t)NN * G * 2);
    float* Dv     = (float*)(base + off); off = alignup(off + (size_t)NN * 4);
    // zeroed region: ccur | GammaP | SjP (one memset)
    size_t zoff = off;
    int*   ccur   = (int*)(base + off);   off += (size_t)CB * 4;
    float* GammaP = (float*)(base + off); off += (size_t)64 * G * 4;
    float* SjP    = (float*)(base + off); off += (size_t)64 * G * 4;
    size_t zsize = off - zoff;
    off = alignup(off);
    int*   rowptr = (int*)(base + off);   off = alignup(off + (size_t)(NN + 1) * 4);
    int2*  cbuf   = (int2*)(base + off);  off = alignup(off + (size_t)CB * CCAP * 8);
    int2*  E      = (int2*)(base + off);  off = alignup(off + (size_t)NE * 8);

    hipMemsetAsync(base + zoff, 0, zsize, stream);

    k_castW1<<<dim3((F0 * F1 + 255) / 256), dim3(256), 0, stream>>>(W1, W1t);
    k_fused1<<<dim3(3 * NPASS), dim3(256), 0, stream>>>(
        H, W1t, XW, row, col, ev, ccur, cbuf);
    k_passB<<<dim3(CB), dim3(256), 0, stream>>>(cbuf, ccur, rowptr, E);
    k_spmm1<<<dim3(NN / 16), dim3(256), 0, stream>>>(XW, rowptr, E, b1, W2, Z, Dv);
    k_head<<<dim3(NN / 4), dim3(256), 0, stream>>>(Z, rowptr, E, b2, Wl, bl, Dv, Yb, GammaP);
    k_loss<<<dim3(NN / 4), dim3(256), 0, stream>>>(Yb, rowptr, E, SjP);
    k_final<<<dim3(1), dim3(64), 0, stream>>>(GammaP, SjP, (float*)d_out);
}

// Round 11
// 341.801 us; speedup vs baseline: 1.0738x; 1.0271x over previous
//
#include <hip/hip_runtime.h>

// GCN forward + NCut loss on MI355X.
// R22: passB parallelism — coarse bucket refined 256 -> 64 rows
//      (CB 196 -> 784, CCAP 10240 -> 2560, same 16MB cbuf). passB grid
//      0.77 -> 3.06 blocks/CU, 4x less serial work + atomics per block,
//      64-wide scan. passA shift/mask 8->6 bits. All else = R21 (best 351us).
// loss = 16 - sum_j S_j/Gamma_j,  S_j = sum_e w_e Y[r,j] Y[c,j]

constexpr int NN = 50000;
constexpr int NE = 1600000;
constexpr int F0 = 512;
constexpr int F1 = 256;
constexpr int G  = 16;
constexpr int CB   = 784;      // coarse buckets: row>>6 (64 rows each)
constexpr int CCAP = 2560;     // capacity per coarse bucket (mean 2048, +11sd)
constexpr int CHUNK = 4096;    // edges per passA block
constexpr int NPASS = 391;     // passA chunks (NE/CHUNK rounded up)
constexpr int ECH = 1024;      // k_spmm1 LDS E-chunk (recs)
// grid = 3*391 = 1173: stripe of 3 blocks = {GEMM, passA, GEMM}

typedef short  s16x8 __attribute__((ext_vector_type(8)));
typedef float  f32x4 __attribute__((ext_vector_type(4)));
typedef float  f32x2 __attribute__((ext_vector_type(2)));
typedef int    i32x4 __attribute__((ext_vector_type(4)));
typedef int    i32x2 __attribute__((ext_vector_type(2)));
typedef float  fv4   __attribute__((ext_vector_type(4)));

static __device__ __forceinline__ unsigned short f2bf(float f) {
    union { float f; unsigned u; } v; v.f = f;
    unsigned r = (v.u + 0x7FFFu + ((v.u >> 16) & 1u)) >> 16;   // RNE
    return (unsigned short)r;
}
static __device__ __forceinline__ float bf2f(unsigned short u) {
    union { unsigned u; float f; } v; v.u = (unsigned)u << 16;
    return v.f;
}

// async global->LDS, 16B per lane; lds addr must be wave-uniform (HW adds lane*16)
static __device__ __forceinline__ void glds16(const void* g, void* l) {
    __builtin_amdgcn_global_load_lds(
        (const __attribute__((address_space(1))) unsigned int*)g,
        (__attribute__((address_space(3))) unsigned int*)l,
        16, 0, 0);
}

// pack 8 f32 -> 8 bf16 (RNE), matching f2bf bit-exactly
static __device__ __forceinline__ s16x8 pack8(f32x4 a, f32x4 b) {
    union { unsigned u[4]; s16x8 v; } r;
    asm("v_cvt_pk_bf16_f32 %0, %1, %2" : "=v"(r.u[0]) : "v"(a.x), "v"(a.y));
    asm("v_cvt_pk_bf16_f32 %0, %1, %2" : "=v"(r.u[1]) : "v"(a.z), "v"(a.w));
    asm("v_cvt_pk_bf16_f32 %0, %1, %2" : "=v"(r.u[2]) : "v"(b.x), "v"(b.y));
    asm("v_cvt_pk_bf16_f32 %0, %1, %2" : "=v"(r.u[3]) : "v"(b.z), "v"(b.w));
    return r.v;
}

// ---------------- W1 pre-cast+transpose ----------------
__global__ __launch_bounds__(256) void k_castW1(const float* __restrict__ W1, unsigned short* __restrict__ W1t) {
    int idx = blockIdx.x * 256 + threadIdx.x;
    if (idx < F0 * F1) {
        int k = idx >> 8, n = idx & 255;
        W1t[n * F0 + k] = f2bf(W1[idx]);
    }
}

// ---------------- fused: GEMM1 (bf16 MFMA -> fp8 XW)  ∪  passA (coarse scatter) ----------------
__global__ __launch_bounds__(256) void k_fused1(const float* __restrict__ H,
                                                const unsigned short* __restrict__ W1t,
                                                unsigned char* __restrict__ XW,
                                                const int* __restrict__ row, const int* __restrict__ col,
                                                const float* __restrict__ ev,
                                                int* __restrict__ ccur, int2* __restrict__ cbuf) {
    // As: f32 [128][64] linear+swizzled slots, 32768 B | Bs: bf16 [128][64], 16384 B
    __shared__ __align__(16) unsigned char smem[49152];
    const int bid = blockIdx.x;
    const int tid = threadIdx.x;
    const int stripe = bid / 3;
    const int pos = bid - stripe * 3;      // 0,1,2

    if (pos != 1) {
        // ================= GEMM1 tile =================
        const int gidx = stripe * 2 + (pos >> 1);     // 0..781
        const int lane = tid & 63;
        const int wave = tid >> 6;
        const int bm = (gidx >> 1) * 128;
        const int bn = (gidx & 1) * 128;
        const int m_off = (wave & 1) * 64;
        const int n_off = (wave >> 1) * 64;
        const int l15  = lane & 15;
        const int quad = lane >> 4;

        f32x4 acc[4][4];
#pragma unroll
        for (int i = 0; i < 4; ++i)
#pragma unroll
            for (int j = 0; j < 4; ++j) acc[i][j] = (f32x4)0.f;

        // staging address precompute (swizzle: slot ^= row&7, within-row permute)
        const int arow16 = tid >> 4;                     // A: 16 lanes/row (256B row)
        const int slA    = (tid & 15) ^ (arow16 & 7);    // f32 slot16 source index
        const int browB  = tid >> 3;                     // B: 8 lanes/row (128B row)
        const int slB    = (tid & 7) ^ (browB & 7);      // bf16 slot16 source index
        const int wvB    = wave * 1024;                  // wave-uniform LDS sub-base

#define STAGE(K0)                                                              \
        do {                                                                   \
            _Pragma("unroll")                                                  \
            for (int p = 0; p < 8; ++p) {                                      \
                int gr = bm + p * 16 + arow16;                                 \
                gr = gr < NN ? gr : NN - 1;                                    \
                glds16(&H[(size_t)gr * F0 + (K0) + slA * 4],                   \
                       smem + p * 4096 + wvB);                                 \
            }                                                                  \
            _Pragma("unroll")                                                  \
            for (int p = 0; p < 4; ++p)                                        \
                glds16(&W1t[(size_t)(bn + p * 32 + browB) * F0 + (K0) + slB * 8], \
                       smem + 32768 + p * 4096 + wvB);                         \
        } while (0)

        STAGE(0);
        asm volatile("s_waitcnt vmcnt(0)" ::: "memory");
        __syncthreads();
        for (int k0 = 0; k0 < F0; k0 += 64) {
#pragma unroll
            for (int kk6 = 0; kk6 < 2; ++kk6) {
                const int kk = kk6 * 32;
                s16x8 af[4], bfr[4];
#pragma unroll
                for (int mi = 0; mi < 4; ++mi) {
                    const int r = m_off + mi * 16 + l15;
                    const int sw = r & 7;
                    const int s0 = (kk >> 2) + quad * 2;
                    const char* rb = (const char*)smem + r * 256;
                    f32x4 v0 = *(const f32x4*)(rb + (((s0    ) ^ sw) << 4));
                    f32x4 v1 = *(const f32x4*)(rb + (((s0 + 1) ^ sw) << 4));
                    af[mi] = pack8(v0, v1);
                }
#pragma unroll
                for (int ni = 0; ni < 4; ++ni) {
                    const int r = n_off + ni * 16 + l15;
                    const int sb = (kk >> 3) + quad;
                    bfr[ni] = *(const s16x8*)((const char*)smem + 32768 + r * 128
                                              + ((sb ^ (r & 7)) << 4));
                }
#pragma unroll
                for (int mi = 0; mi < 4; ++mi)
#pragma unroll
                    for (int ni = 0; ni < 4; ++ni)
                        acc[mi][ni] = __builtin_amdgcn_mfma_f32_16x16x32_bf16(af[mi], bfr[ni], acc[mi][ni], 0, 0, 0);
            }
            __syncthreads();                       // all waves done reading buffer
            if (k0 + 64 < F0) {
                STAGE(k0 + 64);
                asm volatile("s_waitcnt vmcnt(0)" ::: "memory");
            }
            __syncthreads();                       // staged data visible
        }
#undef STAGE
#pragma unroll
        for (int mi = 0; mi < 4; ++mi) {
            int r0 = bm + m_off + mi * 16 + quad * 4;
#pragma unroll
            for (int reg = 0; reg < 4; ++reg) {
                int gr = r0 + reg;
                if (gr < NN) {
                    unsigned char* orow = &XW[(size_t)gr * F1 + bn + n_off];
#pragma unroll
                    for (int ni = 0; ni < 4; ++ni) {
                        int pk = __builtin_amdgcn_cvt_pk_fp8_f32(acc[mi][ni][reg], 0.f, 0, false);
                        orow[ni * 16 + l15] = (unsigned char)(pk & 0xff);
                    }
                }
            }
        }
    } else {
        // ================= passA chunk =================
        int* hcnt  = (int*)smem;
        int* hbase = hcnt + CB;
        for (int i = tid; i < CB; i += 256) hcnt[i] = 0;
        __syncthreads();

        const int base4 = stripe * (CHUNK / 4);   // int4 units
        int recx[16]; float recw[16]; int cb[16];
#pragma unroll
        for (int k = 0; k < 4; ++k) {
            int i4 = base4 + k * 256 + tid;
            bool ok = i4 < NE / 4;
            i32x4 r = ok ? __builtin_nontemporal_load(&((const i32x4*)row)[i4]) : (i32x4)0;
            i32x4 c = ok ? __builtin_nontemporal_load(&((const i32x4*)col)[i4]) : (i32x4)0;
            fv4   w = ok ? __builtin_nontemporal_load(&((const fv4*)ev)[i4])   : (fv4)0.f;
            int rr[4] = {r.x, r.y, r.z, r.w};
            int cc[4] = {c.x, c.y, c.z, c.w};
            float ww[4] = {w.x, w.y, w.z, w.w};
#pragma unroll
            for (int j = 0; j < 4; ++j) {
                int slot = k * 4 + j;
                if (ok) {
                    cb[slot] = rr[j] >> 6;
                    atomicAdd(&hcnt[cb[slot]], 1);
                } else {
                    cb[slot] = -1;
                }
                recx[slot] = (cc[j] << 16) | (rr[j] & 63);
                recw[slot] = ww[j];
            }
        }
        __syncthreads();
        for (int i = tid; i < CB; i += 256) {
            int cnt = hcnt[i];
            hbase[i] = (cnt > 0) ? atomicAdd(&ccur[i], cnt) : 0;
            hcnt[i] = 0;                                   // reuse as local cursor
        }
        __syncthreads();
#pragma unroll
        for (int slot = 0; slot < 16; ++slot) {
            if (cb[slot] >= 0) {
                int p = hbase[cb[slot]] + atomicAdd(&hcnt[cb[slot]], 1);
                cbuf[(size_t)cb[slot] * CCAP + p] = make_int2(recx[slot], __float_as_int(recw[slot]));
            }
        }
    }
}

// ---------------- passB: build rowptr slice + fine scatter (64 rows/bucket) ----------------
__global__ __launch_bounds__(256) void k_passB(const int2* __restrict__ cbuf, const int* __restrict__ ccur,
                                               int* __restrict__ rowptr, int2* __restrict__ E) {
    __shared__ int cnt[64];
    __shared__ int scn[64];
    __shared__ int red[4];
    const int cbk = blockIdx.x;     // 0..783
    const int tid = threadIdx.x;
    if (tid < 64) cnt[tid] = 0;

    // base = sum(ccur[0..cbk))
    int b = 0;
    for (int i = tid; i < cbk; i += 256) b += ccur[i];
#pragma unroll
    for (int off = 1; off < 64; off <<= 1) b += __shfl_xor(b, off, 64);
    if ((tid & 63) == 0) red[tid >> 6] = b;
    __syncthreads();
    const int base = red[0] + red[1] + red[2] + red[3];

    const int total = ccur[cbk];
    const int2* src = cbuf + (size_t)cbk * CCAP;
    for (int i = tid; i < total; i += 256) atomicAdd(&cnt[src[i].x & 63], 1);
    __syncthreads();

    if (tid < 64) scn[tid] = cnt[tid];
    __syncthreads();
    for (int off = 1; off < 64; off <<= 1) {
        int t = (tid >= off && tid < 64) ? scn[tid - off] : 0;
        __syncthreads();
        if (tid < 64) scn[tid] += t;
        __syncthreads();
    }
    if (tid < 64) {
        const int excl = scn[tid] - cnt[tid];
        const int r = (cbk << 6) + tid;
        if (r <= NN) rowptr[r] = base + excl;   // block 781 covers rowptr[NN]=NE
        cnt[tid] = base + excl;                 // reuse as cursor
    }
    __syncthreads();
    for (int i = tid; i < total; i += 256) {
        int2 rec = src[i];
        int rl = rec.x & 63;
        int c  = (int)((unsigned)rec.x >> 16);
        int p = atomicAdd(&cnt[rl], 1);
        E[p] = make_int2(c << 8, rec.y);
    }
}

// ---------------- SPMM1 + bias + relu + fused GEMM2 (fp8 gather, LDS-E + dbuf + pk_fma) ----------------
// W2 LDS layout: dword j*320 + lane16*20 + t (2-way banks = free).
// Block's E segment [rowptr[b*16], rowptr[b*16+16]) staged in LDS chunks.
__global__ __launch_bounds__(256) void k_spmm1(const unsigned char* __restrict__ XW, const int* __restrict__ rowptr,
                                               const int2* __restrict__ E,
                                               const float* __restrict__ b1, const float* __restrict__ W2,
                                               unsigned short* __restrict__ Z, float* __restrict__ Dv) {
    __shared__ float W2P[G * 320];   // 20480 B
    __shared__ i32x2 Esh[ECH];       // 8192 B
    const int tid = threadIdx.x;
#pragma unroll
    for (int it = 0; it < 16; ++it) {
        int elem = it * 256 + tid;            // 0..4095 = (j, l, t)
        int j = elem >> 8;
        int l = (elem >> 4) & 15;
        int t = elem & 15;
        W2P[j * 320 + l * 20 + t] = W2[(l * 16 + t) * 16 + j];
    }
    const int lane16 = tid & 15;
    const int loff = lane16 * 16;                   // byte offset into 256B fp8 row
    const int n = blockIdx.x * 16 + (tid >> 4);     // 16 nodes per block, 4 per wave
    const int nb0 = rowptr[blockIdx.x * 16];
    const int nb1 = rowptr[blockIdx.x * 16 + 16];
    const int s = rowptr[n];
    const int e = rowptr[n + 1];
    const i32x2* E2 = (const i32x2*)E;

    f32x2 acc2[8];                 // dim pairs: acc2[2q]=(4q,4q+1), acc2[2q+1]=(4q+2,4q+3)
#pragma unroll
    for (int q = 0; q < 8; ++q) acc2[q] = (f32x2)0.f;
    float wsum = 0.f;

#define GATH8(GG, WW, BASE)                                        \
        _Pragma("unroll")                                          \
        for (int k = 0; k < 8; ++k) {                              \
            i32x2 ed = Esh[(BASE) - w0 + k];                       \
            WW[k] = __int_as_float(ed.y);                          \
            GG[k] = *(const uint4*)(XW + ed.x + loff);             \
        }
#define COMP8(GG, WW)                                              \
        _Pragma("unroll")                                          \
        for (int k = 0; k < 8; ++k) {                              \
            const unsigned gw[4] = {GG[k].x, GG[k].y, GG[k].z, GG[k].w}; \
            f32x2 wp; wp.x = WW[k]; wp.y = WW[k];                  \
            _Pragma("unroll")                                      \
            for (int q = 0; q < 4; ++q) {                          \
                f32x2 lo = __builtin_amdgcn_cvt_pk_f32_fp8(gw[q], false); \
                f32x2 hi = __builtin_amdgcn_cvt_pk_f32_fp8(gw[q], true);  \
                acc2[2 * q]     = __builtin_elementwise_fma(lo, wp, acc2[2 * q]);     \
                acc2[2 * q + 1] = __builtin_elementwise_fma(hi, wp, acc2[2 * q + 1]); \
            }                                                      \
            wsum += WW[k];                                         \
        }

    for (int w0 = nb0; w0 < nb1; w0 += ECH) {
        const int wend = (w0 + ECH < nb1) ? (w0 + ECH) : nb1;
        __syncthreads();                    // all groups done with prev chunk
        for (int t = tid; t < wend - w0; t += 256)
            Esh[t] = __builtin_nontemporal_load(&E2[w0 + t]);
        __syncthreads();                    // chunk visible

        const int gs = (s > w0) ? s : w0;
        const int ge = (e < wend) ? e : wend;

        uint4 ggA[8], ggB[8];
        float wA[8], wB[8];
        int i = gs;
        if (i + 8 <= ge) { GATH8(ggA, wA, i) }
        while (i + 24 <= ge) {
            GATH8(ggB, wB, i + 8)
            COMP8(ggA, wA)
            GATH8(ggA, wA, i + 16)
            COMP8(ggB, wB)
            i += 16;
        }
        if (i + 16 <= ge) {
            GATH8(ggB, wB, i + 8)
            COMP8(ggA, wA)
            COMP8(ggB, wB)
            i += 16;
        } else if (i + 8 <= ge) {
            COMP8(ggA, wA)
            i += 8;
        }
        // tail < 8 recs
        for (; i < ge; i += 4) {
            int of4[4]; float w4v[4];
#pragma unroll
            for (int k = 0; k < 4; ++k) {
                int idx = i + k;
                bool ok = idx < ge;
                i32x2 ed = Esh[(ok ? idx : gs) - w0];
                of4[k] = ed.x; w4v[k] = ok ? __int_as_float(ed.y) : 0.f;
            }
            uint4 gg[4];
#pragma unroll
            for (int k = 0; k < 4; ++k)
                gg[k] = *(const uint4*)(XW + of4[k] + loff);
#pragma unroll
            for (int k = 0; k < 4; ++k) {
                const unsigned gw[4] = {gg[k].x, gg[k].y, gg[k].z, gg[k].w};
                f32x2 wp; wp.x = w4v[k]; wp.y = w4v[k];
#pragma unroll
                for (int q = 0; q < 4; ++q) {
                    f32x2 lo = __builtin_amdgcn_cvt_pk_f32_fp8(gw[q], false);
                    f32x2 hi = __builtin_amdgcn_cvt_pk_f32_fp8(gw[q], true);
                    acc2[2 * q]     = __builtin_elementwise_fma(lo, wp, acc2[2 * q]);
                    acc2[2 * q + 1] = __builtin_elementwise_fma(hi, wp, acc2[2 * q + 1]);
                }
                wsum += w4v[k];
            }
        }
    }
#undef GATH8
#undef COMP8

    if (lane16 == 0) Dv[n] = wsum;

    // h = relu(acc + b1), in place (lane owns dims loff..loff+15)
#pragma unroll
    for (int q = 0; q < 4; ++q) {
        float4 bb = *(const float4*)&b1[loff + q * 4];
        acc2[2 * q].x     = fmaxf(acc2[2 * q].x     + bb.x, 0.f);
        acc2[2 * q].y     = fmaxf(acc2[2 * q].y     + bb.y, 0.f);
        acc2[2 * q + 1].x = fmaxf(acc2[2 * q + 1].x + bb.z, 0.f);
        acc2[2 * q + 1].y = fmaxf(acc2[2 * q + 1].y + bb.w, 0.f);
    }

    float p[G];
#pragma unroll
    for (int j = 0; j < G; ++j) {
        float pj = 0.f;
#pragma unroll
        for (int q = 0; q < 4; ++q) {
            float4 w4 = *(const float4*)&W2P[j * 320 + lane16 * 20 + q * 4];
            pj += acc2[2 * q].x * w4.x + acc2[2 * q].y * w4.y
                + acc2[2 * q + 1].x * w4.z + acc2[2 * q + 1].y * w4.w;
        }
        p[j] = pj;
    }
    // reduce within each 16-lane group (4 levels)
#pragma unroll
    for (int off = 1; off < 16; off <<= 1) {
#pragma unroll
        for (int j = 0; j < G; ++j) p[j] += __shfl_xor(p[j], off, 64);
    }
    if (lane16 == 0) {
        unsigned zp[8];
#pragma unroll
        for (int j = 0; j < 8; ++j)
            zp[j] = (unsigned)f2bf(p[2 * j]) | ((unsigned)f2bf(p[2 * j + 1]) << 16);
        uint4* zo = (uint4*)&Z[n * G];
        zo[0] = make_uint4(zp[0], zp[1], zp[2], zp[3]);
        zo[1] = make_uint4(zp[4], zp[5], zp[6], zp[7]);
    }
}

// ---------------- SPMM2 + head + softmax + Gamma ----------------
__global__ __launch_bounds__(256) void k_head(const unsigned short* __restrict__ Zb, const int* __restrict__ rowptr,
                                              const int2* __restrict__ E,
                                              const float* __restrict__ b2, const float* __restrict__ Wl,
                                              const float* __restrict__ bl, const float* __restrict__ Dv,
                                              unsigned short* __restrict__ Yb, float* __restrict__ GammaP) {
    __shared__ float WlS[G * G];
    __shared__ float gsh[G];
    const int tid = threadIdx.x;
    if (tid < G * G) WlS[tid] = Wl[tid];
    if (tid < G) gsh[tid] = 0.f;
    __syncthreads();
    const int lane = tid & 63;
    const int g = lane >> 3;      // edge slot 0..7
    const int d = lane & 7;       // dword in Z row
    const int n = blockIdx.x * 4 + (tid >> 6);
    const int s = __builtin_amdgcn_readfirstlane(rowptr[n]);
    const int e = __builtin_amdgcn_readfirstlane(rowptr[n + 1]);
    const char* Zc = (const char*)Zb;
    const i32x2* Ev = (const i32x2*)E;

    float a0 = 0.f, a1 = 0.f;
    for (int base = s; base < e; base += 16) {
        int i0 = base + g;
        int i1 = base + 8 + g;
        i32x2 e0 = __builtin_nontemporal_load(&Ev[(i0 < e) ? i0 : s]);
        i32x2 e1 = __builtin_nontemporal_load(&Ev[(i1 < e) ? i1 : s]);
        float w0 = (i0 < e) ? __int_as_float(e0.y) : 0.f;
        float w1 = (i1 < e) ? __int_as_float(e1.y) : 0.f;
        unsigned z0 = *(const unsigned*)(Zc + (e0.x >> 3) + d * 4);
        unsigned z1 = *(const unsigned*)(Zc + (e1.x >> 3) + d * 4);
        a0 = fmaf(w0, bf2f((unsigned short)(z0 & 0xffff)), a0);
        a1 = fmaf(w0, bf2f((unsigned short)(z0 >> 16)), a1);
        a0 = fmaf(w1, bf2f((unsigned short)(z1 & 0xffff)), a0);
        a1 = fmaf(w1, bf2f((unsigned short)(z1 >> 16)), a1);
    }
    a0 += __shfl_xor(a0, 8, 64);  a1 += __shfl_xor(a1, 8, 64);
    a0 += __shfl_xor(a0, 16, 64); a1 += __shfl_xor(a1, 16, 64);
    a0 += __shfl_xor(a0, 32, 64); a1 += __shfl_xor(a1, 32, 64);

    const int j = lane & 15;
    float e0v = __shfl(a0, j >> 1, 64);
    float e1v = __shfl(a1, j >> 1, 64);
    float accj = (j & 1) ? e1v : e0v;

    float h2 = fmaxf(accj + b2[j], 0.f);
    // Wl matvec split across the 4 duplicate lane groups: each group
    // computes 4 k-terms, then 2 shfl_xor combine (serial chain 16 -> 6).
    const int qg = lane >> 4;
    float s3p = 0.f;
#pragma unroll
    for (int t = 0; t < 4; ++t) {
        int k = qg * 4 + t;
        s3p = fmaf(__shfl(h2, k, 64), WlS[k * G + j], s3p);
    }
    s3p += __shfl_xor(s3p, 16, 64);
    s3p += __shfl_xor(s3p, 32, 64);
    float s3 = s3p;
    float h3 = fmaxf(s3 + bl[j], 0.f);
    float m = h3;
    m = fmaxf(m, __shfl_xor(m, 1, 64));
    m = fmaxf(m, __shfl_xor(m, 2, 64));
    m = fmaxf(m, __shfl_xor(m, 4, 64));
    m = fmaxf(m, __shfl_xor(m, 8, 64));
    float ex = __expf(h3 - m);
    float se = ex;
    se += __shfl_xor(se, 1, 64);
    se += __shfl_xor(se, 2, 64);
    se += __shfl_xor(se, 4, 64);
    se += __shfl_xor(se, 8, 64);
    float y = ex / se;
    if (lane < G) {
        Yb[n * G + j] = f2bf(y);
        atomicAdd(&gsh[j], y * Dv[n]);
    }
    __syncthreads();
    if (tid < G) atomicAdd(&GammaP[(blockIdx.x & 63) * G + tid], gsh[tid]);
}

// ---------------- edge loss numerators: S_j = sum_e w Y[r,j]Y[c,j] (slotted) ----------------
__global__ __launch_bounds__(256) void k_loss(const unsigned short* __restrict__ Yb, const int* __restrict__ rowptr,
                                              const int2* __restrict__ E, float* __restrict__ SjP) {
    __shared__ float sjsh[G];
    const int tid = threadIdx.x;
    if (tid < G) sjsh[tid] = 0.f;
    __syncthreads();
    const int lane = tid & 63;
    const int g = lane >> 3;
    const int d = lane & 7;
    const int n = blockIdx.x * 4 + (tid >> 6);
    const int s = __builtin_amdgcn_readfirstlane(rowptr[n]);
    const int e = __builtin_amdgcn_readfirstlane(rowptr[n + 1]);
    const char* Yc = (const char*)Yb;
    const i32x2* Ev = (const i32x2*)E;

    unsigned yr = *(const unsigned*)(Yc + ((size_t)n << 5) + d * 4);
    float y0 = bf2f((unsigned short)(yr & 0xffff));
    float y1 = bf2f((unsigned short)(yr >> 16));

    float s0 = 0.f, s1 = 0.f;
    for (int base = s; base < e; base += 16) {
        int i0 = base + g;
        int i1 = base + 8 + g;
        i32x2 e0 = __builtin_nontemporal_load(&Ev[(i0 < e) ? i0 : s]);
        i32x2 e1 = __builtin_nontemporal_load(&Ev[(i1 < e) ? i1 : s]);
        float w0 = (i0 < e) ? __int_as_float(e0.y) : 0.f;
        float w1 = (i1 < e) ? __int_as_float(e1.y) : 0.f;
        unsigned z0 = *(const unsigned*)(Yc + (e0.x >> 3) + d * 4);
        unsigned z1 = *(const unsigned*)(Yc + (e1.x >> 3) + d * 4);
        s0 = fmaf(w0 * y0, bf2f((unsigned short)(z0 & 0xffff)), s0);
        s1 = fmaf(w0 * y1, bf2f((unsigned short)(z0 >> 16)), s1);
        s0 = fmaf(w1 * y0, bf2f((unsigned short)(z1 & 0xffff)), s0);
        s1 = fmaf(w1 * y1, bf2f((unsigned short)(z1 >> 16)), s1);
    }
    // sum over the 8 edge-slot groups (bits 3..5 of lane)
    s0 += __shfl_xor(s0, 8, 64);  s1 += __shfl_xor(s1, 8, 64);
    s0 += __shfl_xor(s0, 16, 64); s1 += __shfl_xor(s1, 16, 64);
    s0 += __shfl_xor(s0, 32, 64); s1 += __shfl_xor(s1, 32, 64);
    if (lane < 8) {
        atomicAdd(&sjsh[2 * lane],     s0);
        atomicAdd(&sjsh[2 * lane + 1], s1);
    }
    __syncthreads();
    if (tid < G) atomicAdd(&SjP[(blockIdx.x & 63) * G + tid], sjsh[tid]);
}

// ---------------- finalize: loss = 16 - sum_j S_j / Gamma_j ----------------
__global__ void k_final(const float* __restrict__ GammaP, const float* __restrict__ SjP,
                        float* __restrict__ out) {
    const int tid = threadIdx.x;   // 64 threads, j = tid&15 (dup groups harmless)
    const int j = tid & 15;
    float gam = 0.f, sj = 0.f;
    for (int b = 0; b < 64; ++b) {
        gam += GammaP[b * G + j];
        sj  += SjP[b * G + j];
    }
    float v = sj / gam;
    v += __shfl_xor(v, 1, 64);
    v += __shfl_xor(v, 2, 64);
    v += __shfl_xor(v, 4, 64);
    v += __shfl_xor(v, 8, 64);
    if (tid == 0) out[0] = 16.0f - v;
}

// ---------------- launcher ----------------
static inline size_t alignup(size_t x) { return (x + 255) & ~(size_t)255; }

extern "C" void kernel_launch(void* const* d_in, const int* in_sizes, int n_in,
                              void* d_out, int out_size, void* d_ws, size_t ws_size,
                              hipStream_t stream) {
    const float* H  = (const float*)d_in[0];
    const int*   ei = (const int*)d_in[1];
    const float* ev = (const float*)d_in[2];
    const float* W1 = (const float*)d_in[3];
    const float* b1 = (const float*)d_in[4];
    const float* W2 = (const float*)d_in[5];
    const float* b2 = (const float*)d_in[6];
    const float* Wl = (const float*)d_in[7];
    const float* bl = (const float*)d_in[8];
    const int* row = ei;
    const int* col = ei + NE;

    char* base = (char*)d_ws;
    size_t off = 0;
    unsigned char*  XW  = (unsigned char*)(base + off);  off = alignup(off + (size_t)NN * F1);
    unsigned short* W1t = (unsigned short*)(base + off); off = alignup(off + (size_t)F0 * F1 * 2);
    unsigned short* Z   = (unsigned short*)(base + off); off = alignup(off + (size_t)NN * G * 2);
    unsigned short* Yb  = (unsigned short*)(base + off); off = alignup(off + (size_t)NN * G * 2);
    float* Dv     = (float*)(base + off); off = alignup(off + (size_t)NN * 4);
    // zeroed region: ccur | GammaP | SjP (one memset)
    size_t zoff = off;
    int*   ccur   = (int*)(base + off);   off += (size_t)CB * 4;
    float* GammaP = (float*)(base + off); off += (size_t)64 * G * 4;
    float* SjP    = (float*)(base + off); off += (size_t)64 * G * 4;
    size_t zsize = off - zoff;
    off = alignup(off);
    int*   rowptr = (int*)(base + off);   off = alignup(off + (size_t)(NN + 1) * 4);
    int2*  cbuf   = (int2*)(base + off);  off = alignup(off + (size_t)CB * CCAP * 8);
    int2*  E      = (int2*)(base + off);  off = alignup(off + (size_t)NE * 8);

    hipMemsetAsync(base + zoff, 0, zsize, stream);

    k_castW1<<<dim3((F0 * F1 + 255) / 256), dim3(256), 0, stream>>>(W1, W1t);
    k_fused1<<<dim3(3 * NPASS), dim3(256), 0, stream>>>(
        H, W1t, XW, row, col, ev, ccur, cbuf);
    k_passB<<<dim3(CB), dim3(256), 0, stream>>>(cbuf, ccur, rowptr, E);
    k_spmm1<<<dim3(NN / 16), dim3(256), 0, stream>>>(XW, rowptr, E, b1, W2, Z, Dv);
    k_head<<<dim3(NN / 4), dim3(256), 0, stream>>>(Z, rowptr, E, b2, Wl, bl, Dv, Yb, GammaP);
    k_loss<<<dim3(NN / 4), dim3(256), 0, stream>>>(Yb, rowptr, E, SjP);
    k_final<<<dim3(1), dim3(64), 0, stream>>>(GammaP, SjP, (float*)d_out);
}